// Round 5
// baseline (137.360 us; speedup 1.0000x reference)
//
#include <hip/hip_runtime.h>
#include <math.h>

#define N      4096
#define BLOCK  256
#define JW     32                  // j-tile width
#define NITILE (N / BLOCK)         // 16 i-tiles (256 rows each)
#define NTRI   1088                // sum_{t=0..15} (128 - 8t)

// s(e) = sum_k 1/(1 + c_k*e), c_k = e^{-t_k}, t = {0.5,1,2,4} = Pn(e)/Pd(e)
#define PN0 4.0f
#define PN1 3.384183069f
#define PN2 0.750655861f
#define PN3 0.036699475f
#define PD1 1.128061023f
#define PD2 0.375327930f
#define PD3 0.036699475f
#define PD4 0.000553084f

// ws layout (float/int view): [0] = ticket counter (int), [16 + 2k] = num_k,
// [17 + 2k] = den_k.  First 128 B zeroed by a memset node each launch.
#define WS_CTR   0
#define WS_ACC   16

__device__ __forceinline__ int tri_off(int t) { return 132 * t - 4 * t * t; }

// (BLOCK, 4): 128-VGPR budget. (BLOCK, 8) in round 4 capped VGPRs at 32 and
// spilled the PAIR2 live set to scratch inside the inner loop -> 3x regression
// (VALUBusy 70% -> 19%). Do not re-tighten.
__global__ __launch_bounds__(BLOCK, 4) void lddt_main_kernel(
    const float* __restrict__ pred, const float* __restrict__ truec,
    const int* __restrict__ is_dna, const int* __restrict__ is_rna,
    const int* __restrict__ cmask, float* __restrict__ ws,
    float* __restrict__ out, int nblk_total, int b)
{
    const int L     = blockIdx.x;     // 0..NTRI-1
    const int batch = blockIdx.z;
    const int tid   = threadIdx.x;

    int itile = 0;
#pragma unroll
    for (int u = 1; u < NITILE; ++u) itile += (L >= tri_off(u)) ? 1 : 0;
    const int jseg = 8 * itile + (L - tri_off(itile));
    const bool diag = (jseg < 8 * itile + 8);   // j-range overlaps i-range

    const int i = itile * BLOCK + tid;

    const float* pb = pred  + (size_t)batch * N * 3;
    const float* tb = truec + (size_t)batch * N * 3;
    const int* dnab = is_dna + (size_t)batch * N;
    const int* rnab = is_rna + (size_t)batch * N;
    const int* cmb  = cmask  + (size_t)batch * N;

    // jP = {px,py,pz, nuc?675:0}, jT = {tx,ty,tz, cm?1:0}
    __shared__ float4 jP[JW], jT[JW];
    const int j0 = jseg * JW;
    if (tid < JW) {
        const int j = j0 + tid;
        jP[tid] = make_float4(pb[j*3+0], pb[j*3+1], pb[j*3+2],
                              (dnab[j] | rnab[j]) ? 675.0f : 0.0f);
        jT[tid] = make_float4(tb[j*3+0], tb[j*3+1], tb[j*3+2],
                              cmb[j] ? 1.0f : 0.0f);
    }
    __syncthreads();

    const float pix = pb[i*3+0], piy = pb[i*3+1], piz = pb[i*3+2];
    const float tix = tb[i*3+0], tiy = tb[i*3+1], tiz = tb[i*3+2];
    const float inuc01 = (dnab[i] | rnab[i]) ? 1.0f : 0.0f;
    const float icm    = cmb[i] ? 1.0f : 0.0f;

    float num = 0.0f, den = 0.0f;

    // per-pair partial: numer poly NN, denom poly ND, mask M
#define PAIR(K, NEED_TRI, NN, ND, M)                                           \
    {                                                                          \
        const float4 P = jP[K];                                                \
        const float4 T = jT[K];                                                \
        float dxp = pix - P.x, dyp = piy - P.y, dzp = piz - P.z;               \
        float d2p = fmaf(dxp, dxp, fmaf(dyp, dyp, dzp * dzp));                 \
        float dp  = __builtin_amdgcn_sqrtf(d2p);                               \
        float dxt = tix - T.x, dyt = tiy - T.y, dzt = tiz - T.z;               \
        float d2t = fmaf(dxt, dxt, fmaf(dyt, dyt, dzt * dzt));                 \
        float dt  = __builtin_amdgcn_sqrtf(d2t);                               \
        float dd  = fminf(fabsf(dt - dp), 10.0f);                              \
        float e   = __expf(dd);                                                \
        NN = fmaf(e, fmaf(e, fmaf(e, PN3, PN2), PN1), PN0);                    \
        ND = fmaf(e, fmaf(e, fmaf(e, fmaf(e, PD4, PD3), PD2), PD1), 1.0f);     \
        float cutsq = fmaf(inuc01, P.w, 225.0f);                               \
        bool keep = (d2t < cutsq);                                             \
        if (NEED_TRI) keep = keep && (j0 + (K) > i);                           \
        M = keep ? T.w : 0.0f;                                                 \
    }

    // two pairs share one reciprocal: n1/d1 + n2/d2 = (n1 d2 + n2 d1) rcp(d1 d2)
#define PAIR2(JJ, NEED_TRI)                                                    \
    {                                                                          \
        float n1, d1, m1, n2, d2, m2;                                          \
        PAIR(JJ, NEED_TRI, n1, d1, m1)                                         \
        PAIR((JJ) + 1, NEED_TRI, n2, d2, m2)                                   \
        float t1 = m1 * n1, t2 = m2 * n2;                                      \
        float nm = fmaf(t1, d2, t2 * d1);                                      \
        num = fmaf(nm, __builtin_amdgcn_rcpf(d1 * d2), num);                   \
        den += m1 + m2;                                                        \
    }

    if (diag) {
#pragma unroll 4
        for (int jj = 0; jj < JW; jj += 2) PAIR2(jj, true)
    } else {
#pragma unroll 4
        for (int jj = 0; jj < JW; jj += 2) PAIR2(jj, false)
    }
#undef PAIR2
#undef PAIR

    // symmetry x2 and threshold-mean /4:  num *= 2/4, den *= 2; gate by cm_i
    num *= 0.5f * icm;
    den *= 2.0f * icm;

    for (int off = 32; off > 0; off >>= 1) {
        num += __shfl_down(num, off);
        den += __shfl_down(den, off);
    }
    __shared__ float rn[BLOCK / 64], rd[BLOCK / 64];
    const int wid = tid >> 6, lane = tid & 63;
    if (lane == 0) { rn[wid] = num; rd[wid] = den; }
    __syncthreads();

    if (tid == 0) {
        float tn = rn[0] + rn[1] + rn[2] + rn[3];
        float td = rd[0] + rd[1] + rd[2] + rd[3];
        atomicAdd(&ws[WS_ACC + 2 * batch + 0], tn);
        atomicAdd(&ws[WS_ACC + 2 * batch + 1], td);
        __threadfence();                         // adds visible before ticket
        int old = atomicAdd((int*)ws + WS_CTR, 1);
        if (old == nblk_total - 1) {             // last block: finalize
            __threadfence();
            float acc = 0.0f;
            for (int k = 0; k < b; ++k) {
                float nm = __hip_atomic_load(&ws[WS_ACC + 2 * k + 0],
                                             __ATOMIC_RELAXED, __HIP_MEMORY_SCOPE_AGENT);
                float dn = __hip_atomic_load(&ws[WS_ACC + 2 * k + 1],
                                             __ATOMIC_RELAXED, __HIP_MEMORY_SCOPE_AGENT);
                acc += nm / fmaxf(dn, 1.0f);
            }
            out[0] = 1.0f - acc / (float)b;
        }
    }
}

extern "C" void kernel_launch(void* const* d_in, const int* in_sizes, int n_in,
                              void* d_out, int out_size, void* d_ws, size_t ws_size,
                              hipStream_t stream) {
    const float* pred  = (const float*)d_in[0];
    const float* truec = (const float*)d_in[1];
    const int* is_dna  = (const int*)d_in[2];
    const int* is_rna  = (const int*)d_in[3];
    const int* cmask   = (const int*)d_in[4];
    float* out = (float*)d_out;
    float* ws  = (float*)d_ws;

    const int b = in_sizes[2] / N;

    // zero ticket counter + accumulators (ws is poisoned 0xAA before every launch)
    hipMemsetAsync(ws, 0, 128, stream);

    dim3 grid(NTRI, 1, b);   // 1088 x b = 2176 blocks -> 8.5 blocks/CU
    lddt_main_kernel<<<grid, BLOCK, 0, stream>>>(pred, truec, is_dna, is_rna,
                                                 cmask, ws, out, NTRI * b, b);
}

// Round 6
// 83.006 us; speedup vs baseline: 1.6548x; 1.6548x over previous
//
#include <hip/hip_runtime.h>
#include <math.h>

#define N      4096
#define BLOCK  256
#define JW     32                  // j-tile width
#define NITILE (N / BLOCK)         // 16 i-tiles (256 rows each)
#define NTRI   1088                // sum_{t=0..15} (128 - 8t)

// s(e) = sum_k 1/(1 + c_k*e), c_k = e^{-t_k}, t = {0.5,1,2,4} = Pn(e)/Pd(e)
#define PN0 4.0f
#define PN1 3.384183069f
#define PN2 0.750655861f
#define PN3 0.036699475f
#define PD1 1.128061023f
#define PD2 0.375327930f
#define PD3 0.036699475f
#define PD4 0.000553084f

__device__ __forceinline__ int tri_off(int t) { return 132 * t - 4 * t * t; }

// NOTE (R4/R5 post-mortem): do NOT fuse the final reduction into this kernel
// via global atomics + __threadfence + ticket. That chain serialized 2176
// wave-0s on two cache lines (~35 ns each, cross-XCD RMW + L2 writeback) ->
// main kernel 28 -> 82 us, OccupancyPercent 27% (one lingering wave/block),
// VALUBusy 19%. Plain per-block partial stores + a separate ~4 us finalize
// dispatch is 5x cheaper than the "saved" launch.
__global__ __launch_bounds__(BLOCK, 4) void lddt_main_kernel(
    const float* __restrict__ pred, const float* __restrict__ truec,
    const int* __restrict__ is_dna, const int* __restrict__ is_rna,
    const int* __restrict__ cmask, float* __restrict__ ws)
{
    const int L     = blockIdx.x;     // 0..NTRI-1, linear upper-tri tile id
    const int batch = blockIdx.z;
    const int tid   = threadIdx.x;

    int itile = 0;
#pragma unroll
    for (int u = 1; u < NITILE; ++u) itile += (L >= tri_off(u)) ? 1 : 0;
    const int jseg = 8 * itile + (L - tri_off(itile));
    const bool diag = (jseg < 8 * itile + 8);   // j-range overlaps i-range

    const int i = itile * BLOCK + tid;

    const float* pb = pred  + (size_t)batch * N * 3;
    const float* tb = truec + (size_t)batch * N * 3;
    const int* dnab = is_dna + (size_t)batch * N;
    const int* rnab = is_rna + (size_t)batch * N;
    const int* cmb  = cmask  + (size_t)batch * N;

    // jP = {px,py,pz, nuc?675:0}, jT = {tx,ty,tz, cm?1:0}
    __shared__ float4 jP[JW], jT[JW];
    const int j0 = jseg * JW;
    if (tid < JW) {
        const int j = j0 + tid;
        jP[tid] = make_float4(pb[j*3+0], pb[j*3+1], pb[j*3+2],
                              (dnab[j] | rnab[j]) ? 675.0f : 0.0f);
        jT[tid] = make_float4(tb[j*3+0], tb[j*3+1], tb[j*3+2],
                              cmb[j] ? 1.0f : 0.0f);
    }
    __syncthreads();

    const float pix = pb[i*3+0], piy = pb[i*3+1], piz = pb[i*3+2];
    const float tix = tb[i*3+0], tiy = tb[i*3+1], tiz = tb[i*3+2];
    const float inuc01 = (dnab[i] | rnab[i]) ? 1.0f : 0.0f;
    const float icm    = cmb[i] ? 1.0f : 0.0f;

    float num = 0.0f, den = 0.0f;

    // per-pair partial: numer poly NN, denom poly ND, mask M
#define PAIR(K, NEED_TRI, NN, ND, M)                                           \
    {                                                                          \
        const float4 P = jP[K];                                                \
        const float4 T = jT[K];                                                \
        float dxp = pix - P.x, dyp = piy - P.y, dzp = piz - P.z;               \
        float d2p = fmaf(dxp, dxp, fmaf(dyp, dyp, dzp * dzp));                 \
        float dp  = __builtin_amdgcn_sqrtf(d2p);                               \
        float dxt = tix - T.x, dyt = tiy - T.y, dzt = tiz - T.z;               \
        float d2t = fmaf(dxt, dxt, fmaf(dyt, dyt, dzt * dzt));                 \
        float dt  = __builtin_amdgcn_sqrtf(d2t);                               \
        float dd  = fminf(fabsf(dt - dp), 10.0f);                              \
        float e   = __expf(dd);                                                \
        NN = fmaf(e, fmaf(e, fmaf(e, PN3, PN2), PN1), PN0);                    \
        ND = fmaf(e, fmaf(e, fmaf(e, fmaf(e, PD4, PD3), PD2), PD1), 1.0f);     \
        float cutsq = fmaf(inuc01, P.w, 225.0f);                               \
        bool keep = (d2t < cutsq);                                             \
        if (NEED_TRI) keep = keep && (j0 + (K) > i);                           \
        M = keep ? T.w : 0.0f;                                                 \
    }

    // two pairs share one reciprocal: n1/d1 + n2/d2 = (n1 d2 + n2 d1) rcp(d1 d2)
#define PAIR2(JJ, NEED_TRI)                                                    \
    {                                                                          \
        float n1, d1, m1, n2, d2, m2;                                          \
        PAIR(JJ, NEED_TRI, n1, d1, m1)                                         \
        PAIR((JJ) + 1, NEED_TRI, n2, d2, m2)                                   \
        float t1 = m1 * n1, t2 = m2 * n2;                                      \
        float nm = fmaf(t1, d2, t2 * d1);                                      \
        num = fmaf(nm, __builtin_amdgcn_rcpf(d1 * d2), num);                   \
        den += m1 + m2;                                                        \
    }

    if (diag) {
#pragma unroll 4
        for (int jj = 0; jj < JW; jj += 2) PAIR2(jj, true)
    } else {
#pragma unroll 4
        for (int jj = 0; jj < JW; jj += 2) PAIR2(jj, false)
    }
#undef PAIR2
#undef PAIR

    // symmetry x2 and threshold-mean /4:  num *= 2/4, den *= 2; gate by cm_i
    num *= 0.5f * icm;
    den *= 2.0f * icm;

    for (int off = 32; off > 0; off >>= 1) {
        num += __shfl_down(num, off);
        den += __shfl_down(den, off);
    }
    __shared__ float rn[BLOCK / 64], rd[BLOCK / 64];
    const int wid = tid >> 6, lane = tid & 63;
    if (lane == 0) { rn[wid] = num; rd[wid] = den; }
    __syncthreads();
    if (tid == 0) {
        float tn = rn[0] + rn[1] + rn[2] + rn[3];
        float td = rd[0] + rd[1] + rd[2] + rd[3];
        const int bid = batch * NTRI + L;
        ws[bid * 2 + 0] = tn;   // plain stores to distinct slots -> no init,
        ws[bid * 2 + 1] = td;   // no atomics, no fence
    }
}

__global__ __launch_bounds__(BLOCK) void finalize_kernel(
    const float* __restrict__ ws, float* __restrict__ out, int b)
{
    __shared__ float sn[4], sd[4];
    float acc = 0.0f;
    for (int k = 0; k < b; ++k) {
        float n = 0.0f, d = 0.0f;
        for (int p = threadIdx.x; p < NTRI; p += BLOCK) {
            n += ws[(k * NTRI + p) * 2 + 0];
            d += ws[(k * NTRI + p) * 2 + 1];
        }
        for (int off = 32; off > 0; off >>= 1) {
            n += __shfl_down(n, off);
            d += __shfl_down(d, off);
        }
        if ((threadIdx.x & 63) == 0) { sn[threadIdx.x >> 6] = n; sd[threadIdx.x >> 6] = d; }
        __syncthreads();
        if (threadIdx.x == 0) {
            float tn = sn[0] + sn[1] + sn[2] + sn[3];
            float td = sd[0] + sd[1] + sd[2] + sd[3];
            acc += tn / fmaxf(td, 1.0f);
        }
        __syncthreads();
    }
    if (threadIdx.x == 0) out[0] = 1.0f - acc / (float)b;
}

extern "C" void kernel_launch(void* const* d_in, const int* in_sizes, int n_in,
                              void* d_out, int out_size, void* d_ws, size_t ws_size,
                              hipStream_t stream) {
    const float* pred  = (const float*)d_in[0];
    const float* truec = (const float*)d_in[1];
    const int* is_dna  = (const int*)d_in[2];
    const int* is_rna  = (const int*)d_in[3];
    const int* cmask   = (const int*)d_in[4];
    float* out = (float*)d_out;
    float* ws  = (float*)d_ws;

    const int b = in_sizes[2] / N;

    dim3 grid(NTRI, 1, b);   // 1088 x b = 2176 blocks -> 8.5 blocks/CU
    lddt_main_kernel<<<grid, BLOCK, 0, stream>>>(pred, truec, is_dna, is_rna, cmask, ws);
    finalize_kernel<<<1, BLOCK, 0, stream>>>(ws, out, b);
}

// Round 7
// 82.503 us; speedup vs baseline: 1.6649x; 1.0061x over previous
//
#include <hip/hip_runtime.h>
#include <math.h>

#define N      4096
#define BLOCK  256
#define JW     32                  // j-tile width
#define NITILE (N / BLOCK)         // 16 i-tiles (256 rows each)
#define NTRI   1088                // sum_{t=0..15} (128 - 8t)
#define NQ     (JW / 4)            // 8 PAIR4 groups

typedef float v4f __attribute__((ext_vector_type(4)));

// s(e) = sum_k 1/(1 + c_k*e), c_k = e^{-t_k}, t = {0.5,1,2,4} = Pn(e)/Pd(e)
#define PN0 4.0f
#define PN1 3.384183069f
#define PN2 0.750655861f
#define PN3 0.036699475f
#define PD1 1.128061023f
#define PD2 0.375327930f
#define PD3 0.036699475f
#define PD4 0.000553084f

__device__ __forceinline__ int tri_off(int t) { return 132 * t - 4 * t * t; }
__device__ __forceinline__ v4f splat(float x) { return (v4f){x, x, x, x}; }

// NOTE (R4/R5 post-mortem): do NOT fuse the final reduction in via global
// atomics + __threadfence + ticket: 2176 serialized wave-0s on two cache
// lines cost ~75 us (main 28 -> 82 us). Plain per-block stores + separate
// finalize dispatch wins.
// NOTE (R4): __launch_bounds__(256,8) caps VGPRs at 32 -> inner-loop scratch
// spill, 3x regression. Keep (256,4).
__global__ __launch_bounds__(BLOCK, 4) void lddt_main_kernel(
    const float* __restrict__ pred, const float* __restrict__ truec,
    const int* __restrict__ is_dna, const int* __restrict__ is_rna,
    const int* __restrict__ cmask, float* __restrict__ ws)
{
    const int L     = blockIdx.x;     // 0..NTRI-1, linear upper-tri tile id
    const int batch = blockIdx.z;
    const int tid   = threadIdx.x;

    int itile = 0;
#pragma unroll
    for (int u = 1; u < NITILE; ++u) itile += (L >= tri_off(u)) ? 1 : 0;
    const int jseg = 8 * itile + (L - tri_off(itile));
    const bool diag = (jseg < 8 * itile + 8);   // j-range overlaps i-range

    const int i = itile * BLOCK + tid;

    const float* pb = pred  + (size_t)batch * N * 3;
    const float* tb = truec + (size_t)batch * N * 3;
    const int* dnab = is_dna + (size_t)batch * N;
    const int* rnab = is_rna + (size_t)batch * N;
    const int* cmb  = cmask  + (size_t)batch * N;

    // SoA j-tile staging: broadcast ds_read_b128 of each component array
    // yields operands pre-packed for v_pk_* (4 consecutive j's per v4f).
    __shared__ v4f spx[NQ], spy[NQ], spz[NQ], snw[NQ];
    __shared__ v4f stx[NQ], sty[NQ], stz[NQ], scw[NQ];
    const int j0 = jseg * JW;
    if (tid < JW) {
        const int j = j0 + tid;
        ((float*)spx)[tid] = pb[j*3+0];
        ((float*)spy)[tid] = pb[j*3+1];
        ((float*)spz)[tid] = pb[j*3+2];
        ((float*)snw)[tid] = (dnab[j] | rnab[j]) ? 675.0f : 0.0f;  // (30^2-15^2)
        ((float*)stx)[tid] = tb[j*3+0];
        ((float*)sty)[tid] = tb[j*3+1];
        ((float*)stz)[tid] = tb[j*3+2];
        ((float*)scw)[tid] = cmb[j] ? 1.0f : 0.0f;
    }
    __syncthreads();

    const float pix = pb[i*3+0], piy = pb[i*3+1], piz = pb[i*3+2];
    const float tix = tb[i*3+0], tiy = tb[i*3+1], tiz = tb[i*3+2];
    const float inuc01 = (dnab[i] | rnab[i]) ? 1.0f : 0.0f;
    const float icm    = cmb[i] ? 1.0f : 0.0f;

    const v4f pix4 = splat(pix), piy4 = splat(piy), piz4 = splat(piz);
    const v4f tix4 = splat(tix), tiy4 = splat(tiy), tiz4 = splat(tiz);
    const v4f base = splat(225.0f);          // 15^2
    const v4f inuc4 = splat(inuc01);

    float num = 0.0f;
    v4f den4 = splat(0.0f);

    // 4 pairs per iteration, packed f32 math; 2 shared rcps per group
#define PAIR4(Q, NEED_TRI)                                                     \
    {                                                                          \
        const v4f Px = spx[Q], Py = spy[Q], Pz = spz[Q], Pw = snw[Q];          \
        const v4f Tx = stx[Q], Ty = sty[Q], Tz = stz[Q], Tw = scw[Q];          \
        v4f dxp = pix4 - Px, dyp = piy4 - Py, dzp = piz4 - Pz;                 \
        v4f d2p = dxp * dxp + dyp * dyp + dzp * dzp;                           \
        v4f dxt = tix4 - Tx, dyt = tiy4 - Ty, dzt = tiz4 - Tz;                 \
        v4f d2t = dxt * dxt + dyt * dyt + dzt * dzt;                           \
        v4f dp, dt;                                                            \
        dp.x = __builtin_amdgcn_sqrtf(d2p.x); dt.x = __builtin_amdgcn_sqrtf(d2t.x); \
        dp.y = __builtin_amdgcn_sqrtf(d2p.y); dt.y = __builtin_amdgcn_sqrtf(d2t.y); \
        dp.z = __builtin_amdgcn_sqrtf(d2p.z); dt.z = __builtin_amdgcn_sqrtf(d2t.z); \
        dp.w = __builtin_amdgcn_sqrtf(d2p.w); dt.w = __builtin_amdgcn_sqrtf(d2t.w); \
        v4f dd = dt - dp;                                                      \
        v4f e;                                                                 \
        e.x = __expf(fminf(fabsf(dd.x), 10.0f));                               \
        e.y = __expf(fminf(fabsf(dd.y), 10.0f));                               \
        e.z = __expf(fminf(fabsf(dd.z), 10.0f));                               \
        e.w = __expf(fminf(fabsf(dd.w), 10.0f));                               \
        v4f NN = ((e * splat(PN3) + splat(PN2)) * e + splat(PN1)) * e + splat(PN0); \
        v4f ND = (((e * splat(PD4) + splat(PD3)) * e + splat(PD2)) * e + splat(PD1)) * e + splat(1.0f); \
        v4f cut = base + inuc4 * Pw;                                           \
        v4f m;                                                                 \
        { bool k0 = d2t.x < cut.x, k1 = d2t.y < cut.y,                         \
           k2 = d2t.z < cut.z, k3 = d2t.w < cut.w;                             \
          if (NEED_TRI) { const int jb = j0 + 4 * (Q);                         \
            k0 = k0 && (jb + 0 > i); k1 = k1 && (jb + 1 > i);                  \
            k2 = k2 && (jb + 2 > i); k3 = k3 && (jb + 3 > i); }                \
          m.x = k0 ? Tw.x : 0.0f; m.y = k1 ? Tw.y : 0.0f;                      \
          m.z = k2 ? Tw.z : 0.0f; m.w = k3 ? Tw.w : 0.0f; }                    \
        v4f t = m * NN;                                                        \
        den4 += m;                                                             \
        float na = fmaf(t.x, ND.y, t.y * ND.x);                                \
        num = fmaf(na, __builtin_amdgcn_rcpf(ND.x * ND.y), num);               \
        float nb = fmaf(t.z, ND.w, t.w * ND.z);                                \
        num = fmaf(nb, __builtin_amdgcn_rcpf(ND.z * ND.w), num);               \
    }

    if (diag) {
#pragma unroll 2
        for (int q = 0; q < NQ; ++q) PAIR4(q, true)
    } else {
#pragma unroll 2
        for (int q = 0; q < NQ; ++q) PAIR4(q, false)
    }
#undef PAIR4

    float den = den4.x + den4.y + den4.z + den4.w;

    // symmetry x2, threshold-mean /4, gate by cm_i
    num *= 0.5f * icm;
    den *= 2.0f * icm;

    for (int off = 32; off > 0; off >>= 1) {
        num += __shfl_down(num, off);
        den += __shfl_down(den, off);
    }
    __shared__ float rn[BLOCK / 64], rd[BLOCK / 64];
    const int wid = tid >> 6, lane = tid & 63;
    if (lane == 0) { rn[wid] = num; rd[wid] = den; }
    __syncthreads();
    if (tid == 0) {
        float tn = rn[0] + rn[1] + rn[2] + rn[3];
        float td = rd[0] + rd[1] + rd[2] + rd[3];
        const int bid = batch * NTRI + L;
        ws[bid * 2 + 0] = tn;   // plain stores to distinct slots -> no init,
        ws[bid * 2 + 1] = td;   // no atomics, no fence
    }
}

__global__ __launch_bounds__(BLOCK) void finalize_kernel(
    const float* __restrict__ ws, float* __restrict__ out, int b)
{
    __shared__ float sn[4], sd[4];
    float acc = 0.0f;
    for (int k = 0; k < b; ++k) {
        float n = 0.0f, d = 0.0f;
        for (int p = threadIdx.x; p < NTRI; p += BLOCK) {
            n += ws[(k * NTRI + p) * 2 + 0];
            d += ws[(k * NTRI + p) * 2 + 1];
        }
        for (int off = 32; off > 0; off >>= 1) {
            n += __shfl_down(n, off);
            d += __shfl_down(d, off);
        }
        if ((threadIdx.x & 63) == 0) { sn[threadIdx.x >> 6] = n; sd[threadIdx.x >> 6] = d; }
        __syncthreads();
        if (threadIdx.x == 0) {
            float tn = sn[0] + sn[1] + sn[2] + sn[3];
            float td = sd[0] + sd[1] + sd[2] + sd[3];
            acc += tn / fmaxf(td, 1.0f);
        }
        __syncthreads();
    }
    if (threadIdx.x == 0) out[0] = 1.0f - acc / (float)b;
}

extern "C" void kernel_launch(void* const* d_in, const int* in_sizes, int n_in,
                              void* d_out, int out_size, void* d_ws, size_t ws_size,
                              hipStream_t stream) {
    const float* pred  = (const float*)d_in[0];
    const float* truec = (const float*)d_in[1];
    const int* is_dna  = (const int*)d_in[2];
    const int* is_rna  = (const int*)d_in[3];
    const int* cmask   = (const int*)d_in[4];
    float* out = (float*)d_out;
    float* ws  = (float*)d_ws;

    const int b = in_sizes[2] / N;

    dim3 grid(NTRI, 1, b);   // 1088 x b = 2176 blocks -> 8.5 blocks/CU
    lddt_main_kernel<<<grid, BLOCK, 0, stream>>>(pred, truec, is_dna, is_rna, cmask, ws);
    finalize_kernel<<<1, BLOCK, 0, stream>>>(ws, out, b);
}